// Round 7
// baseline (258.638 us; speedup 1.0000x reference)
//
#include <hip/hip_runtime.h>

// ChamferLoss: B=4, N=M=8192, D=3, fp32.
// loss = mean_b[ mean(pred2gt) + mean(gt2pred) + max(pred2gt) ]
// R7: MFMA path. R4-R6 proved the fp32 VALU stream is capped (~54% issue,
// scalar fma=2cy, pk_fma=4cy => fixed 157TF FLOP rate; floor ~37us).
// Move dot products to the matrix pipe: 32x32x16 bf16 MFMA with hi/lo split:
//   A row m (K=16): [xh0..2, xh0..2, xl0..2, 1, 1, 0...]        (x of row m)
//   B col n (K=16): [-2yh0..2, -2yl0..2, -2yh0..2, y2h, y2l, 0] (y of col n)
//   C[m][n] = x2[m]  =>  D = x2 + y2 - 2(xh.yh + xh.yl + xl.yh) ~ d^2 (fp32)
// Dropped xl.yl ~ 2^-18 => |err| ~1e-4 << 4.5e-2 threshold. Per 32-y tile:
// 1 ds_read_b128 + 2 MFMA (co-issued) + 32 v_min = 64 VALU cy / 2048 pairs.
// Epilogue: LDS transpose (stride 33 words, conflict-free) -> 64 atomicMins.

typedef short  s16x8  __attribute__((ext_vector_type(8)));
typedef float  f32x16 __attribute__((ext_vector_type(16)));

#define BATCH 4
#define NPTS  8192
#define TPB   256
#define XPB   256            // x-points per block (4 waves x 64)
#define NXC   (NPTS / XPB)   // 32 x-chunks
#define YS    4              // y slices
#define SLICE (NPTS / YS)    // 2048
#define SUBY  1024           // y per LDS staging batch (32 KB)
#define NSUB  (SLICE / SUBY) // 2
#define NTILE (SUBY / 32)    // 32 y-tiles per batch

__device__ __forceinline__ unsigned int bft(float f) {   // fp32 -> bf16 (trunc)
    return __float_as_uint(f) >> 16;
}
__device__ __forceinline__ float bfv(unsigned int s) {   // bf16 -> fp32
    return __uint_as_float(s << 16);
}

__global__ __launch_bounds__(TPB, 4)
void nn_mfma(const float* __restrict__ pred, const float* __restrict__ gt,
             unsigned int* __restrict__ pmin) {
    const int xc = blockIdx.x, sl = blockIdx.y, bd = blockIdx.z;
    const int b = bd >> 1, dir = bd & 1;
    const float* xp = (dir ? gt : pred) + (size_t)b * NPTS * 3;
    const float* yp = (dir ? pred : gt) + (size_t)b * NPTS * 3;

    // 33792 B: y staging (32768 B) reused as transpose scratch (4x64x33 fp32)
    __shared__ uint4 smem[2112];

    const int t = threadIdx.x;
    const int w = t >> 6, l = t & 63;
    const int m32 = l & 31, hh = l >> 5;   // lane's k-half

    // ---- one-time: A frags (2 x-tiles of 32) + C frags (x2 per C/D row) ----
    s16x8 af[2];
    float x2j[2];
    #pragma unroll
    for (int j = 0; j < 2; ++j) {
        const int xi = xc * XPB + w * 64 + j * 32 + m32;
        const float c0 = xp[xi * 3], c1 = xp[xi * 3 + 1], c2 = xp[xi * 3 + 2];
        x2j[j] = c0 * c0 + c1 * c1 + c2 * c2;
        const unsigned int xh0 = bft(c0), xh1 = bft(c1), xh2 = bft(c2);
        const unsigned int xl0 = bft(c0 - bfv(xh0));
        const unsigned int xl1 = bft(c1 - bfv(xh1));
        const unsigned int xl2 = bft(c2 - bfv(xh2));
        s16x8 a;                       // k = hh*8 + e
        a[0] = (short)(hh ? xl2 : xh0);
        a[1] = (short)(hh ? 0x3F80u : xh1);   // 1.0 bf16 (picks up y2h)
        a[2] = (short)(hh ? 0x3F80u : xh2);   // 1.0 bf16 (picks up y2l)
        a[3] = (short)(hh ? 0u : xh0);
        a[4] = (short)(hh ? 0u : xh1);
        a[5] = (short)(hh ? 0u : xh2);
        a[6] = (short)(hh ? 0u : xl0);
        a[7] = (short)(hh ? 0u : xl1);
        af[j] = a;
    }
    f32x16 cf0, cf1;
    #pragma unroll
    for (int r = 0; r < 16; ++r) {     // C/D row = (r&3)+8*(r>>2)+4*hh (m74/m101)
        const int row = (r & 3) + 8 * (r >> 2) + 4 * hh;
        cf0[r] = __shfl(x2j[0], row, 64);
        cf1[r] = __shfl(x2j[1], row, 64);
    }
    f32x16 mn0, mn1;
    #pragma unroll
    for (int r = 0; r < 16; ++r) { mn0[r] = 3.4e38f; mn1[r] = 3.4e38f; }

    // ---- y loop: stage SUBY transformed y's to LDS, then 32 MFMA tiles ----
    const int ybase0 = sl * SLICE;
    for (int sb = 0; sb < NSUB; ++sb) {
        #pragma unroll
        for (int j = 0; j < 4; ++j) {
            const int loc = t + j * TPB;
            const int yi = ybase0 + sb * SUBY + loc;
            const float a0 = yp[yi * 3], a1 = yp[yi * 3 + 1], a2 = yp[yi * 3 + 2];
            const unsigned int yh0 = bft(a0), yh1 = bft(a1), yh2 = bft(a2);
            const float l0 = a0 - bfv(yh0), l1 = a1 - bfv(yh1), l2 = a2 - bfv(yh2);
            const unsigned int nh0 = bft(-2.f * bfv(yh0));   // exact in bf16
            const unsigned int nh1 = bft(-2.f * bfv(yh1));
            const unsigned int nh2 = bft(-2.f * bfv(yh2));
            const unsigned int nl0 = bft(-2.f * l0), nl1 = bft(-2.f * l1), nl2 = bft(-2.f * l2);
            const float y2 = a0 * a0 + a1 * a1 + a2 * a2;
            const unsigned int q2h = bft(y2);
            const unsigned int q2l = bft(y2 - bfv(q2h));
            uint4 w0, w1;                       // 16 bf16 slots, k-order
            w0.x = nh0 | (nh1 << 16);
            w0.y = nh2 | (nl0 << 16);
            w0.z = nl1 | (nl2 << 16);
            w0.w = nh0 | (nh1 << 16);
            w1.x = nh2 | (q2h << 16);
            w1.y = q2l;
            w1.z = 0u; w1.w = 0u;
            smem[loc * 2]     = w0;
            smem[loc * 2 + 1] = w1;
        }
        __syncthreads();
        const short* sb16 = (const short*)smem;
        #pragma unroll 4
        for (int t32 = 0; t32 < NTILE; ++t32) {
            const s16x8 bf = *(const s16x8*)(sb16 + (t32 * 32 + m32) * 16 + hh * 8);
            f32x16 e0 = __builtin_amdgcn_mfma_f32_32x32x16_bf16(af[0], bf, cf0, 0, 0, 0);
            mn0 = __builtin_elementwise_min(mn0, e0);
            f32x16 e1 = __builtin_amdgcn_mfma_f32_32x32x16_bf16(af[1], bf, cf1, 0, 0, 0);
            mn1 = __builtin_elementwise_min(mn1, e1);
        }
        __syncthreads();   // before next staging overwrite / epilogue reuse
    }

    // ---- epilogue: LDS transpose (stride 33 -> conflict-free), 1 atomic/lane ----
    float* wsb = (float*)smem + w * (64 * 33);
    #pragma unroll
    for (int r = 0; r < 16; ++r) {
        const int row = (r & 3) + 8 * (r >> 2) + 4 * hh;
        wsb[row * 33 + m32]        = mn0[r];
        wsb[(32 + row) * 33 + m32] = mn1[r];
    }
    __syncthreads();
    float acc = 3.4e38f;
    #pragma unroll
    for (int c = 0; c < 32; ++c) acc = fminf(acc, wsb[l * 33 + c]);
    const float d = fmaxf(acc, 0.f);                 // sqdist >= 0
    atomicMin(&pmin[(size_t)bd * NPTS + xc * XPB + w * 64 + l], __float_as_uint(d));
}

// One 1024-thread block: 128 threads per bd; sum + max per bd; write out[0].
__global__ __launch_bounds__(1024)
void reduce_all(const unsigned int* __restrict__ pmin,
                float* __restrict__ out) {
    const int t  = threadIdx.x;
    const int bd = t >> 7;              // 0..7
    const int l  = t & 127;
    const unsigned int* base = pmin + (size_t)bd * NPTS;
    float sum = 0.f, mx = -1.f;
    #pragma unroll
    for (int i = 0; i < NPTS / 128; ++i) {
        const float f = __uint_as_float(base[i * 128 + l]);
        sum += f;
        mx = fmaxf(mx, f);
    }
    #pragma unroll
    for (int off = 32; off; off >>= 1) {
        sum += __shfl_down(sum, off, 64);
        mx = fmaxf(mx, __shfl_down(mx, off, 64));
    }
    __shared__ float ss[16], sm[16];
    if ((t & 63) == 0) { ss[t >> 6] = sum; sm[t >> 6] = mx; }
    __syncthreads();
    if (t == 0) {
        float acc = 0.f;
        #pragma unroll
        for (int d = 0; d < 8; ++d) {
            const float S = ss[2 * d] + ss[2 * d + 1];
            const float M = fmaxf(sm[2 * d], sm[2 * d + 1]);
            // even bd (pred2gt): mean + max ; odd bd (gt2pred): mean only.
            acc += S * (1.f / NPTS) + ((d & 1) ? 0.f : M);
        }
        out[0] = acc * (1.f / BATCH);
    }
}

extern "C" void kernel_launch(void* const* d_in, const int* in_sizes, int n_in,
                              void* d_out, int out_size, void* d_ws, size_t ws_size,
                              hipStream_t stream) {
    const float* pred = (const float*)d_in[0];
    const float* gt   = (const float*)d_in[1];

    unsigned int* pmin = (unsigned int*)d_ws;   // 2*B*NPTS uints = 256 KB

    hipMemsetAsync(pmin, 0xFF, (size_t)2 * BATCH * NPTS * 4, stream);  // +inf sentinel

    dim3 g1(NXC, YS, 2 * BATCH);   // 32 x 4 x 8 = 1024 blocks (4/CU)
    nn_mfma<<<g1, TPB, 0, stream>>>(pred, gt, pmin);
    reduce_all<<<dim3(1), 1024, 0, stream>>>(pmin, (float*)d_out);
}

// Round 8
// 85.944 us; speedup vs baseline: 3.0094x; 3.0094x over previous
//
#include <hip/hip_runtime.h>

// ChamferLoss: B=4, N=M=8192, D=3, fp32.
// loss = mean_b[ mean(pred2gt) + mean(gt2pred) + max(pred2gt) ]
// R8: MFMA path, despilled. R7 verified the bf16 hi/lo-split math (absmax 0)
// but spilled (62+55 MB scratch) and hit 1.57M LDS conflicts. Fix:
//  - yprep kernel precomputes per-y B-frags (32 B) to global, tile-major
//    [tile][half][n] so the hot kernel's read is base + lane*16 (coalesced).
//  - hot kernel: NO LDS, no barriers; J=2 x-tiles/wave, C=0, ~100 VGPR.
//  - epilogue: xor-butterfly min across 32 cols + predicated reg-select,
//    one atomicMin per lane.
//   A row m (K=16): [xh0..2, xh0..2, xl0..2, 1, 1, 0...]
//   B col n (K=16): [-2yh0..2, -2yl0..2, -2yh0..2, y2h, y2l, 0]
//   D = y2 - 2(xh.yh + xh.yl + xl.yh); d2 = x2 + min_y D  (xl.yl ~2^-18 dropped)

typedef short  s16x8  __attribute__((ext_vector_type(8)));
typedef float  f32x16 __attribute__((ext_vector_type(16)));

#define BATCH 4
#define NPTS  8192
#define TPB   256
#define YS    4                    // y slices per (b,dir)
#define YTILES (NPTS / 32)         // 256 y-tiles total
#define YTS   (YTILES / YS)        // 64 y-tiles per slice
#define XPB   256                  // x per block: 4 waves x 2 tiles x 32
#define NXC   (NPTS / XPB)         // 32

__device__ __forceinline__ unsigned int bft(float f) { return __float_as_uint(f) >> 16; }
__device__ __forceinline__ float bfv(unsigned int s) { return __uint_as_float(s << 16); }

// Precompute B-frags: bfrag[arr(2)][b(4)][tile(256)][half(2)][n(32)] x uint4.
__global__ __launch_bounds__(TPB)
void yprep(const float* __restrict__ pred, const float* __restrict__ gt,
           uint4* __restrict__ bfrag) {
    const int gid = blockIdx.x * TPB + threadIdx.x;    // 0..65535
    const int arr = gid >> 15;                         // 0=pred, 1=gt
    const int rem = gid & 32767;                       // b*NPTS + yi
    const int yi  = rem & (NPTS - 1);
    const float* y = (arr ? gt : pred) + (size_t)rem * 3;
    const float a0 = y[0], a1 = y[1], a2 = y[2];
    const unsigned int yh0 = bft(a0), yh1 = bft(a1), yh2 = bft(a2);
    const float l0 = a0 - bfv(yh0), l1 = a1 - bfv(yh1), l2 = a2 - bfv(yh2);
    const unsigned int nh0 = bft(-2.f * bfv(yh0));     // exact in bf16
    const unsigned int nh1 = bft(-2.f * bfv(yh1));
    const unsigned int nh2 = bft(-2.f * bfv(yh2));
    const unsigned int nl0 = bft(-2.f * l0), nl1 = bft(-2.f * l1), nl2 = bft(-2.f * l2);
    const float y2 = a0 * a0 + a1 * a1 + a2 * a2;
    const unsigned int q2h = bft(y2);
    const unsigned int q2l = bft(y2 - bfv(q2h));
    uint4 w0, w1;                                      // k-order halves
    w0.x = nh0 | (nh1 << 16);
    w0.y = nh2 | (nl0 << 16);
    w0.z = nl1 | (nl2 << 16);
    w0.w = nh0 | (nh1 << 16);
    w1.x = nh2 | (q2h << 16);
    w1.y = q2l;
    w1.z = 0u; w1.w = 0u;
    const size_t base = ((size_t)(gid >> 13) * YTILES + (yi >> 5)) * 64;  // (arr*4+b)
    bfrag[base + (yi & 31)]      = w0;
    bfrag[base + 32 + (yi & 31)] = w1;
}

__global__ __launch_bounds__(TPB, 4)
void nn_mfma(const float* __restrict__ pred, const float* __restrict__ gt,
             const uint4* __restrict__ bfrag, unsigned int* __restrict__ pmin) {
    const int xc = blockIdx.x, sl = blockIdx.y, bd = blockIdx.z;
    const int b = bd >> 1, dir = bd & 1;
    const float* xp = (dir ? gt : pred) + (size_t)b * NPTS * 3;
    const int yarr = dir ? 0 : 1;                      // y = dir ? pred : gt
    const uint4* bfb = bfrag + (size_t)(yarr * BATCH + b) * YTILES * 64;

    const int t = threadIdx.x;
    const int w = t >> 6, l = t & 63;
    const int m32 = l & 31, hh = l >> 5;
    const int xbase = xc * XPB + w * 64;

    // A-frags + x2 for the wave's two 32-row x-tiles.
    s16x8 af[2];
    float x2j[2];
    #pragma unroll
    for (int j = 0; j < 2; ++j) {
        const int xi = xbase + j * 32 + m32;
        const float c0 = xp[xi * 3], c1 = xp[xi * 3 + 1], c2 = xp[xi * 3 + 2];
        x2j[j] = c0 * c0 + c1 * c1 + c2 * c2;
        const unsigned int xh0 = bft(c0), xh1 = bft(c1), xh2 = bft(c2);
        const unsigned int xl0 = bft(c0 - bfv(xh0));
        const unsigned int xl1 = bft(c1 - bfv(xh1));
        const unsigned int xl2 = bft(c2 - bfv(xh2));
        s16x8 a;                                       // k = hh*8 + e
        a[0] = (short)(hh ? xl2 : xh0);
        a[1] = (short)(hh ? 0x3F80u : xh1);            // 1.0 bf16 (y2h)
        a[2] = (short)(hh ? 0x3F80u : xh2);            // 1.0 bf16 (y2l)
        a[3] = (short)(hh ? 0u : xh0);
        a[4] = (short)(hh ? 0u : xh1);
        a[5] = (short)(hh ? 0u : xh2);
        a[6] = (short)(hh ? 0u : xl0);
        a[7] = (short)(hh ? 0u : xl1);
        af[j] = a;
    }

    f32x16 zero, mn0, mn1;
    #pragma unroll
    for (int r = 0; r < 16; ++r) { zero[r] = 0.f; mn0[r] = 3.4e38f; mn1[r] = 3.4e38f; }

    // Hot loop: 2 coalesced 1KB loads + 4 MFMA + 32 v_min3 per iter (4096 pairs).
    const uint4* bp = bfb + (size_t)(sl * YTS) * 64 + l;
    for (int t32 = 0; t32 < YTS; t32 += 2) {
        const s16x8 bf0 = __builtin_bit_cast(s16x8, bp[0]);
        const s16x8 bf1 = __builtin_bit_cast(s16x8, bp[64]);
        bp += 128;
        const f32x16 e00 = __builtin_amdgcn_mfma_f32_32x32x16_bf16(af[0], bf0, zero, 0, 0, 0);
        const f32x16 e01 = __builtin_amdgcn_mfma_f32_32x32x16_bf16(af[0], bf1, zero, 0, 0, 0);
        mn0 = __builtin_elementwise_min(mn0, __builtin_elementwise_min(e00, e01));
        const f32x16 e10 = __builtin_amdgcn_mfma_f32_32x32x16_bf16(af[1], bf0, zero, 0, 0, 0);
        const f32x16 e11 = __builtin_amdgcn_mfma_f32_32x32x16_bf16(af[1], bf1, zero, 0, 0, 0);
        mn1 = __builtin_elementwise_min(mn1, __builtin_elementwise_min(e10, e11));
    }

    // Butterfly min across the 32 cols (stays within each 32-lane half).
    #pragma unroll
    for (int off = 16; off; off >>= 1) {
        #pragma unroll
        for (int r = 0; r < 16; ++r) {
            mn0[r] = fminf(mn0[r], __shfl_xor(mn0[r], off, 64));
            mn1[r] = fminf(mn1[r], __shfl_xor(mn1[r], off, 64));
        }
    }

    // Lane l: r = l&15; lanes (l&31)<16 -> tile0, else tile1. One atomic/lane.
    const int r = l & 15;
    const int row = (r & 3) + 8 * (r >> 2) + 4 * hh;   // C/D row map (m74/m101)
    float v0 = mn0[0], v1 = mn1[0];
    #pragma unroll
    for (int rr = 1; rr < 16; ++rr) {
        v0 = (r == rr) ? mn0[rr] : v0;
        v1 = (r == rr) ? mn1[rr] : v1;
    }
    const float x20 = __shfl(x2j[0], row, 64);
    const float x21 = __shfl(x2j[1], row, 64);
    const bool g1 = (l & 31) >= 16;
    const float d = fmaxf((g1 ? v1 : v0) + (g1 ? x21 : x20), 0.f);
    const int xpt = xbase + (g1 ? 32 : 0) + row;
    atomicMin(&pmin[(size_t)bd * NPTS + xpt], __float_as_uint(d));
}

// One 1024-thread block: 128 threads per bd; sum + max per bd; write out[0].
__global__ __launch_bounds__(1024)
void reduce_all(const unsigned int* __restrict__ pmin, float* __restrict__ out) {
    const int t  = threadIdx.x;
    const int bd = t >> 7;
    const int l  = t & 127;
    const unsigned int* base = pmin + (size_t)bd * NPTS;
    float sum = 0.f, mx = -1.f;
    #pragma unroll
    for (int i = 0; i < NPTS / 128; ++i) {
        const float f = __uint_as_float(base[i * 128 + l]);
        sum += f;
        mx = fmaxf(mx, f);
    }
    #pragma unroll
    for (int off = 32; off; off >>= 1) {
        sum += __shfl_down(sum, off, 64);
        mx = fmaxf(mx, __shfl_down(mx, off, 64));
    }
    __shared__ float ss[16], sm[16];
    if ((t & 63) == 0) { ss[t >> 6] = sum; sm[t >> 6] = mx; }
    __syncthreads();
    if (t == 0) {
        float acc = 0.f;
        #pragma unroll
        for (int d = 0; d < 8; ++d) {
            const float S = ss[2 * d] + ss[2 * d + 1];
            const float M = fmaxf(sm[2 * d], sm[2 * d + 1]);
            acc += S * (1.f / NPTS) + ((d & 1) ? 0.f : M);   // max only for pred2gt
        }
        out[0] = acc * (1.f / BATCH);
    }
}

extern "C" void kernel_launch(void* const* d_in, const int* in_sizes, int n_in,
                              void* d_out, int out_size, void* d_ws, size_t ws_size,
                              hipStream_t stream) {
    const float* pred = (const float*)d_in[0];
    const float* gt   = (const float*)d_in[1];

    unsigned int* pmin = (unsigned int*)d_ws;                       // 256 KB
    uint4* bfrag = (uint4*)((char*)d_ws + (size_t)2 * BATCH * NPTS * 4);  // 2 MB

    hipMemsetAsync(pmin, 0xFF, (size_t)2 * BATCH * NPTS * 4, stream);

    yprep<<<dim3(2 * BATCH * NPTS / TPB), TPB, 0, stream>>>(pred, gt, bfrag);
    dim3 g1(NXC, YS, 2 * BATCH);   // 32 x 4 x 8 = 1024 blocks (4/CU)
    nn_mfma<<<g1, TPB, 0, stream>>>(pred, gt, bfrag, pmin);
    reduce_all<<<dim3(1), 1024, 0, stream>>>(pmin, (float*)d_out);
}